// Round 5
// baseline (1000.133 us; speedup 1.0000x reference)
//
#include <hip/hip_runtime.h>
#include <hip/hip_cooperative_groups.h>
#include <stdint.h>

namespace cg = cooperative_groups;

#define B_   8
#define V_   49152
#define M_   (B_ * V_)        // 393216 GEMM rows
#define CAP_ 48               // fixed edge capacity per row (max Poisson(8) deg << 48)
#define PREP_B 3072           // conv units: V_*16/256

typedef unsigned short ushort_t;
typedef __attribute__((ext_vector_type(8))) short short8;
typedef __attribute__((ext_vector_type(4))) float float4v;

__device__ __forceinline__ float bf2f_lo(unsigned int pk) {
    union { unsigned int u; float f; } x; x.u = pk << 16; return x.f;
}
__device__ __forceinline__ float bf2f_hi(unsigned int pk) {
    union { unsigned int u; float f; } x; x.u = pk & 0xffff0000u; return x.f;
}
__device__ __forceinline__ ushort_t f2bf(float f) {
    union { unsigned int u; float f; } x; x.f = f;
    unsigned int u = x.u;
    unsigned int r = u + 0x7fffu + ((u >> 16) & 1u);   // RNE
    return (ushort_t)(r >> 16);
}
__device__ __forceinline__ unsigned int pack2(float a, float b) {
    return ((unsigned int)f2bf(b) << 16) | (unsigned int)f2bf(a);
}
// acc[0..7] += w * (8 bf16 in p)
__device__ __forceinline__ void fma8(float* acc, float w, const uint4& p) {
    const unsigned int* u = (const unsigned int*)&p;
    #pragma unroll
    for (int i = 0; i < 4; i++) {
        acc[2 * i]     += w * bf2f_lo(u[i]);
        acc[2 * i + 1] += w * bf2f_hi(u[i]);
    }
}

__global__ void fill_sentinel(float* out, int n) {
    int i = blockIdx.x * blockDim.x + threadIdx.x;
    if (i < n) out[i] = 9999.0f;
}

// ---------------- phase-1 unit: conv | prep_w | bucket ----------------
__device__ __forceinline__ void k1_unit(int u, int t,
                                        const float* __restrict__ inp,
                                        ushort_t* __restrict__ x0t,
                                        const int* __restrict__ rows,
                                        const int* __restrict__ cols,
                                        const float* __restrict__ vals, int nnz,
                                        int* __restrict__ cursor,
                                        uint2* __restrict__ e_cv,
                                        const float* __restrict__ wgt,
                                        ushort_t* __restrict__ wBf) {
    if (u < PREP_B) {
        // x0t[(v*8+b)*64 + fi] = bf16(inp[(b*V+v)*64 + fi]); float4 loads, uint2 stores
        int idx = u * 256 + t;              // 0 .. V_*16-1
        int f4 = idx & 15, v = idx >> 4;
        #pragma unroll
        for (int b = 0; b < 8; b++) {
            float4 d = *(const float4*)(inp + ((size_t)b * V_ + v) * 64 + f4 * 4);
            uint2 o = make_uint2(pack2(d.x, d.y), pack2(d.z, d.w));
            *(uint2*)(x0t + ((size_t)v * 8 + b) * 64 + f4 * 4) = o;
        }
    } else if (u < PREP_B + 48) {
        // MFMA B-fragments, Chebyshev fold: kc0' = W0-W2, kc1' = W1, kc2' = 2*W2
        int idx = (u - PREP_B) * 256 + t;   // < 12288
        int j = idx & 7, lane = (idx >> 3) & 63, ntc = (idx >> 9) & 3, kb = idx >> 11;
        int k = kb * 32 + (lane >> 4) * 8 + j;
        int kc = k >> 6, fi = k & 63;
        int fo = ntc * 16 + (lane & 15);
        float w;
        if (kc == 0)      w = wgt[(fi * 3 + 0) * 64 + fo] - wgt[(fi * 3 + 2) * 64 + fo];
        else if (kc == 1) w = wgt[(fi * 3 + 1) * 64 + fo];
        else              w = 2.0f * wgt[(fi * 3 + 2) * 64 + fo];
        wBf[idx] = f2bf(w);
    } else {
        // fixed-capacity bucket: e_cv[r*CAP_ + pos] = {col, val}
        int i = (u - PREP_B - 48) * 256 + t;
        if (i < nnz) {
            int r = rows[i];
            int pos = atomicAdd(&cursor[r], 1);
            if (pos < CAP_)
                e_cv[(size_t)r * CAP_ + pos] = make_uint2((unsigned int)cols[i],
                                                          __float_as_uint(vals[i]));
        }
    }
}

// gather body: rows padded to multiple of 4 (zeroed slots) -> remainder-free
// unroll-4 loop, 8 row loads + 2 edge-record loads in flight. VGPR fits 64.
__device__ __forceinline__ void gather16(const ushort_t* __restrict__ srcbf,
                                         const uint2* __restrict__ e_cv,
                                         int beg, int end, float* acc) {
    for (int e = beg; e < end; e += 4) {
        uint4 E0 = *(const uint4*)(e_cv + e);        // {c0,w0,c1,w1}
        uint4 E1 = *(const uint4*)(e_cv + e + 2);    // {c2,w2,c3,w3}
        float w0 = __uint_as_float(E0.y), w1 = __uint_as_float(E0.w);
        float w2 = __uint_as_float(E1.y), w3 = __uint_as_float(E1.w);
        const ushort_t* p0 = srcbf + ((size_t)E0.x * 512);
        const ushort_t* p1 = srcbf + ((size_t)E0.z * 512);
        const ushort_t* p2 = srcbf + ((size_t)E1.x * 512);
        const ushort_t* p3 = srcbf + ((size_t)E1.z * 512);
        uint4 a0 = *(const uint4*)p0, b0 = *(const uint4*)(p0 + 8);
        uint4 a1 = *(const uint4*)p1, b1 = *(const uint4*)(p1 + 8);
        uint4 a2 = *(const uint4*)p2, b2 = *(const uint4*)(p2 + 8);
        uint4 a3 = *(const uint4*)p3, b3 = *(const uint4*)(p3 + 8);
        fma8(acc, w0, a0); fma8(acc + 8, w0, b0);
        fma8(acc, w1, a1); fma8(acc + 8, w1, b1);
        fma8(acc, w2, a2); fma8(acc + 8, w2, b2);
        fma8(acc, w3, a3); fma8(acc + 8, w3, b3);
    }
}

__device__ __forceinline__ int row_end(const int* cursor, int v) {
    int c = cursor[v];
    if (c > CAP_) c = CAP_;
    return v * CAP_ + ((c + 3) & ~3);
}

// ---------------- phase-2 unit: x1 = L @ x0t (8 vertices per unit) ----------------
__device__ __forceinline__ void spmm1_unit(int u, int t,
                                           const ushort_t* __restrict__ x0t,
                                           const int* __restrict__ cursor,
                                           const uint2* __restrict__ e_cv,
                                           ushort_t* __restrict__ x1) {
    int vi = t >> 5, b = (t >> 2) & 7, f8 = t & 3;
    int v = u * 8 + vi;
    float acc[16];
    #pragma unroll
    for (int i = 0; i < 16; i++) acc[i] = 0.f;
    gather16(x0t + b * 64 + f8 * 16, e_cv, v * CAP_, row_end(cursor, v), acc);
    unsigned int opk[8];
    #pragma unroll
    for (int i = 0; i < 8; i++) opk[i] = pack2(acc[2 * i], acc[2 * i + 1]);
    ushort_t* dst = x1 + ((size_t)v * 8 + b) * 64 + f8 * 16;
    *(uint4*)dst       = make_uint4(opk[0], opk[1], opk[2], opk[3]);
    *(uint4*)(dst + 8) = make_uint4(opk[4], opk[5], opk[6], opk[7]);
}

// ---------------- phase-3 unit: g = L@x1 (LDS) + 64-row GEMM + bias + out ----------
// out = x0*(W0-W2) + x1*W1 + g*(2*W2)   (weight fold done in prep_w)
__device__ __forceinline__ void spmm2_unit(int u, int t,
                                           const ushort_t* __restrict__ x0t,
                                           const ushort_t* __restrict__ x1,
                                           const int* __restrict__ cursor,
                                           const uint2* __restrict__ e_cv,
                                           const ushort_t* __restrict__ wBf,
                                           const float* __restrict__ bias,
                                           float* __restrict__ out) {
    __shared__ ushort_t sh[64 * 72];        // g rows, padded stride 72 shorts (144 B)
    int lane = t & 63, wv = t >> 6;
    int quad = lane >> 4, col = lane & 15;
    int v0 = u * 8;
    int m0 = v0 * 8 + wv * 16;

    // Prefetch GEMM A-fragments (own rows of x0, x1) — overlaps the gather phase.
    size_t arow = (size_t)(m0 + col) * 64 + quad * 8;   // A: row=lane&15, k=quad*8+j
    short8 A0[2], A1[2];
    A0[0] = *(const short8*)(x0t + arow);
    A0[1] = *(const short8*)(x0t + arow + 32);
    A1[0] = *(const short8*)(x1 + arow);
    A1[1] = *(const short8*)(x1 + arow + 32);

    int vi = t >> 5, b = (t >> 2) & 7, f8 = t & 3;
    int v = v0 + vi;
    float acc[16];
    #pragma unroll
    for (int i = 0; i < 16; i++) acc[i] = 0.f;
    gather16(x1 + b * 64 + f8 * 16, e_cv, v * CAP_, row_end(cursor, v), acc);

    // g straight to LDS (no x0 blend — folded into weights)
    unsigned int opk[8];
    #pragma unroll
    for (int i = 0; i < 8; i++) opk[i] = pack2(acc[2 * i], acc[2 * i + 1]);
    int mg = vi * 8 + b;
    ushort_t* dst = sh + mg * 72 + f8 * 16;
    *(uint4*)dst       = make_uint4(opk[0], opk[1], opk[2], opk[3]);
    *(uint4*)(dst + 8) = make_uint4(opk[4], opk[5], opk[6], opk[7]);
    __syncthreads();

    // ---- GEMM phase: wave wv handles rows [wv*16, wv*16+16) of this 64-row tile
    short8 Bf[6][4];
    #pragma unroll
    for (int kb = 0; kb < 6; kb++)
        #pragma unroll
        for (int ntc = 0; ntc < 4; ntc++)
            Bf[kb][ntc] = *(const short8*)(wBf + ((size_t)((kb * 4 + ntc) * 64 + lane)) * 8);

    float bv[4];
    #pragma unroll
    for (int ntc = 0; ntc < 4; ntc++) bv[ntc] = bias[ntc * 16 + col];

    float4v accm[4];
    #pragma unroll
    for (int ntc = 0; ntc < 4; ntc++) accm[ntc] = (float4v){0.f, 0.f, 0.f, 0.f};

    #pragma unroll
    for (int p = 0; p < 2; p++) {
        #pragma unroll
        for (int ntc = 0; ntc < 4; ntc++)
            accm[ntc] = __builtin_amdgcn_mfma_f32_16x16x32_bf16(A0[p], Bf[p][ntc], accm[ntc], 0, 0, 0);
    }
    #pragma unroll
    for (int p = 0; p < 2; p++) {
        #pragma unroll
        for (int ntc = 0; ntc < 4; ntc++)
            accm[ntc] = __builtin_amdgcn_mfma_f32_16x16x32_bf16(A1[p], Bf[2 + p][ntc], accm[ntc], 0, 0, 0);
    }
    #pragma unroll
    for (int p = 0; p < 2; p++) {
        short8 A = *(const short8*)(sh + (wv * 16 + col) * 72 + quad * 8 + p * 32);
        #pragma unroll
        for (int ntc = 0; ntc < 4; ntc++)
            accm[ntc] = __builtin_amdgcn_mfma_f32_16x16x32_bf16(A, Bf[4 + p][ntc], accm[ntc], 0, 0, 0);
    }

    #pragma unroll
    for (int reg = 0; reg < 4; reg++) {
        int m = m0 + quad * 4 + reg;        // C/D: row = quad*4+reg, col = lane&15
        int vv = m >> 3, bb = m & 7;
        float* orow = out + ((size_t)bb * V_ + vv) * 64;
        #pragma unroll
        for (int ntc = 0; ntc < 4; ntc++)
            orow[ntc * 16 + col] = accm[ntc][reg] + bv[ntc];
    }
    __syncthreads();   // protect sh before next grid-stride iteration rewrites it
}

// ---------------- standalone fallback kernels ----------------
__global__ __launch_bounds__(256) void k1_fused(const float* __restrict__ inp,
                                                ushort_t* __restrict__ x0t,
                                                const int* __restrict__ rows,
                                                const int* __restrict__ cols,
                                                const float* __restrict__ vals, int nnz,
                                                int* __restrict__ cursor,
                                                uint2* __restrict__ e_cv,
                                                const float* __restrict__ wgt,
                                                ushort_t* __restrict__ wBf) {
    k1_unit(blockIdx.x, threadIdx.x, inp, x0t, rows, cols, vals, nnz, cursor, e_cv, wgt, wBf);
}

__global__ __launch_bounds__(256) void spmm1_kernel(const ushort_t* __restrict__ x0t,
                                                    const int* __restrict__ cursor,
                                                    const uint2* __restrict__ e_cv,
                                                    ushort_t* __restrict__ x1) {
    spmm1_unit(blockIdx.x, threadIdx.x, x0t, cursor, e_cv, x1);
}

__global__ __launch_bounds__(256) void spmm2_gemm(const ushort_t* __restrict__ x0t,
                                                  const ushort_t* __restrict__ x1,
                                                  const int* __restrict__ cursor,
                                                  const uint2* __restrict__ e_cv,
                                                  const ushort_t* __restrict__ wBf,
                                                  const float* __restrict__ bias,
                                                  float* __restrict__ out) {
    spmm2_unit(blockIdx.x, threadIdx.x, x0t, x1, cursor, e_cv, wBf, bias, out);
}

// ---------------- cooperative mega-kernel: whole pipeline, one dispatch ----------
struct KArgs {
    const float* inp; const float* wgt; const float* bias;
    const int* rows; const int* cols; const float* vals;
    int nnz; int hb;
    int* cursor; uint2* e_cv;
    ushort_t* x0t; ushort_t* x1; ushort_t* wBf;
    float* out;
    uint4* zbase; long long z16;
};

__global__ __launch_bounds__(256, 8) void mega_kernel(KArgs a) {
    cg::grid_group grid = cg::this_grid();
    int t = threadIdx.x;
    int G = gridDim.x;
    // phase 0: zero cursor + e_cv (pads must read {0,0})
    for (long long i = (long long)blockIdx.x * 256 + t; i < a.z16; i += (long long)G * 256)
        a.zbase[i] = make_uint4(0u, 0u, 0u, 0u);
    grid.sync();
    // phase 1: conv | prep_w | bucket
    int n1 = PREP_B + 48 + a.hb;
    for (int u = blockIdx.x; u < n1; u += G)
        k1_unit(u, t, a.inp, a.x0t, a.rows, a.cols, a.vals, a.nnz, a.cursor, a.e_cv, a.wgt, a.wBf);
    grid.sync();
    // phase 2: x1 = L @ x0
    for (int u = blockIdx.x; u < V_ / 8; u += G)
        spmm1_unit(u, t, a.x0t, a.cursor, a.e_cv, a.x1);
    grid.sync();
    // phase 3: g = L @ x1, GEMM, out
    for (int u = blockIdx.x; u < V_ / 8; u += G)
        spmm2_unit(u, t, a.x0t, a.x1, a.cursor, a.e_cv, a.wBf, a.bias, a.out);
}

extern "C" void kernel_launch(void* const* d_in, const int* in_sizes, int n_in,
                              void* d_out, int out_size, void* d_ws, size_t ws_size,
                              hipStream_t stream) {
    const float* inp  = (const float*)d_in[0];
    const float* wgt  = (const float*)d_in[1];
    const float* bias = (const float*)d_in[2];
    const int*   rows = (const int*)d_in[3];
    const int*   cols = (const int*)d_in[4];
    const float* vals = (const float*)d_in[5];
    int nnz = in_sizes[3];
    float* out = (float*)d_out;
    (void)n_in; (void)out_size;

    char* ws = (char*)d_ws;
    size_t o = 0;
    auto alloc = [&](size_t bytes) { void* p = ws + o; o += (bytes + 255) & ~(size_t)255; return p; };
    size_t meta0 = o;
    int*      cursor = (int*)alloc((size_t)V_ * 4);
    uint2*    e_cv   = (uint2*)alloc((size_t)V_ * CAP_ * 8);
    size_t meta_bytes = o - meta0;
    ushort_t* x0t    = (ushort_t*)alloc((size_t)M_ * 64 * 2);
    ushort_t* x1     = (ushort_t*)alloc((size_t)M_ * 64 * 2);
    ushort_t* wBf    = (ushort_t*)alloc(6 * 4 * 64 * 8 * 2);

    if (ws_size < o) {
        fill_sentinel<<<(M_ * 64 + 255) / 256, 256, 0, stream>>>(out, M_ * 64);
        return;
    }

    int hb = (nnz + 255) / 256;

    // Cooperative co-residency: occupancy query (cached), 256 CUs on MI355X.
    static int maxBlkPerCU = -2;
    if (maxBlkPerCU == -2) {
        int mb = 0;
        hipError_t e = hipOccupancyMaxActiveBlocksPerMultiprocessor(&mb, mega_kernel, 256, 0);
        maxBlkPerCU = (e == hipSuccess && mb > 0) ? mb : 0;
    }
    bool done = false;
    if (maxBlkPerCU > 0) {
        int G = maxBlkPerCU * 256;
        if (G > 2048) G = 2048;
        KArgs a;
        a.inp = inp; a.wgt = wgt; a.bias = bias;
        a.rows = rows; a.cols = cols; a.vals = vals;
        a.nnz = nnz; a.hb = hb;
        a.cursor = cursor; a.e_cv = e_cv;
        a.x0t = x0t; a.x1 = x1; a.wBf = wBf;
        a.out = out;
        a.zbase = (uint4*)(ws + meta0);
        a.z16 = (long long)(meta_bytes / 16);
        void* kargs[] = { &a };
        hipError_t e = hipLaunchCooperativeKernel((const void*)mega_kernel,
                                                  dim3(G), dim3(256), kargs, 0, stream);
        done = (e == hipSuccess);
    }
    if (!done) {
        // fallback: 4-node stream pipeline (round-3/4 style, pad-4 gather)
        hipMemsetAsync((char*)ws + meta0, 0, meta_bytes, stream);
        k1_fused<<<PREP_B + 48 + hb, 256, 0, stream>>>(inp, x0t, rows, cols, vals, nnz,
                                                       cursor, e_cv, wgt, wBf);
        spmm1_kernel<<<V_ / 8, 256, 0, stream>>>(x0t, cursor, e_cv, x1);
        spmm2_gemm<<<V_ / 8, 256, 0, stream>>>(x0t, x1, cursor, e_cv, wBf, bias, out);
    }
}

// Round 6
// 491.821 us; speedup vs baseline: 2.0335x; 2.0335x over previous
//
#include <hip/hip_runtime.h>
#include <hip/hip_cooperative_groups.h>
#include <stdint.h>

namespace cg = cooperative_groups;

#define B_   8
#define V_   49152
#define M_   (B_ * V_)        // 393216 GEMM rows
#define CAP_ 48               // fixed edge capacity per row (max Poisson(8) deg << 48)
#define PREP_B 3072           // conv units: V_*16/256

typedef unsigned short ushort_t;
typedef __attribute__((ext_vector_type(8))) short short8;
typedef __attribute__((ext_vector_type(4))) float float4v;

__device__ __forceinline__ float bf2f_lo(unsigned int pk) {
    union { unsigned int u; float f; } x; x.u = pk << 16; return x.f;
}
__device__ __forceinline__ float bf2f_hi(unsigned int pk) {
    union { unsigned int u; float f; } x; x.u = pk & 0xffff0000u; return x.f;
}
__device__ __forceinline__ ushort_t f2bf(float f) {
    union { unsigned int u; float f; } x; x.f = f;
    unsigned int u = x.u;
    unsigned int r = u + 0x7fffu + ((u >> 16) & 1u);   // RNE
    return (ushort_t)(r >> 16);
}
__device__ __forceinline__ unsigned int pack2(float a, float b) {
    return ((unsigned int)f2bf(b) << 16) | (unsigned int)f2bf(a);
}
// acc[0..7] += w * (8 bf16 in p)
__device__ __forceinline__ void fma8(float* acc, float w, const uint4& p) {
    const unsigned int* u = (const unsigned int*)&p;
    #pragma unroll
    for (int i = 0; i < 4; i++) {
        acc[2 * i]     += w * bf2f_lo(u[i]);
        acc[2 * i + 1] += w * bf2f_hi(u[i]);
    }
}

__global__ void fill_sentinel(float* out, int n) {
    int i = blockIdx.x * blockDim.x + threadIdx.x;
    if (i < n) out[i] = 9999.0f;
}

// ---------------- phase-1 unit: conv | prep_w | bucket ----------------
__device__ __forceinline__ void k1_unit(int u, int t,
                                        const float* __restrict__ inp,
                                        ushort_t* __restrict__ x0t,
                                        const int* __restrict__ rows,
                                        const int* __restrict__ cols,
                                        const float* __restrict__ vals, int nnz,
                                        int* __restrict__ cursor,
                                        uint2* __restrict__ e_cv,
                                        const float* __restrict__ wgt,
                                        ushort_t* __restrict__ wBf) {
    if (u < PREP_B) {
        // x0t[(v*8+b)*64 + fi] = bf16(inp[(b*V+v)*64 + fi]); float4 loads, uint2 stores
        int idx = u * 256 + t;              // 0 .. V_*16-1
        int f4 = idx & 15, v = idx >> 4;
        #pragma unroll
        for (int b = 0; b < 8; b++) {
            float4 d = *(const float4*)(inp + ((size_t)b * V_ + v) * 64 + f4 * 4);
            uint2 o = make_uint2(pack2(d.x, d.y), pack2(d.z, d.w));
            *(uint2*)(x0t + ((size_t)v * 8 + b) * 64 + f4 * 4) = o;
        }
    } else if (u < PREP_B + 48) {
        // MFMA B-fragments, Chebyshev fold: kc0' = W0-W2, kc1' = W1, kc2' = 2*W2
        int idx = (u - PREP_B) * 256 + t;   // < 12288
        int j = idx & 7, lane = (idx >> 3) & 63, ntc = (idx >> 9) & 3, kb = idx >> 11;
        int k = kb * 32 + (lane >> 4) * 8 + j;
        int kc = k >> 6, fi = k & 63;
        int fo = ntc * 16 + (lane & 15);
        float w;
        if (kc == 0)      w = wgt[(fi * 3 + 0) * 64 + fo] - wgt[(fi * 3 + 2) * 64 + fo];
        else if (kc == 1) w = wgt[(fi * 3 + 1) * 64 + fo];
        else              w = 2.0f * wgt[(fi * 3 + 2) * 64 + fo];
        wBf[idx] = f2bf(w);
    } else {
        // fixed-capacity bucket: e_cv[r*CAP_ + pos] = {col, val}
        int i = (u - PREP_B - 48) * 256 + t;
        if (i < nnz) {
            int r = rows[i];
            int pos = atomicAdd(&cursor[r], 1);
            if (pos < CAP_)
                e_cv[(size_t)r * CAP_ + pos] = make_uint2((unsigned int)cols[i],
                                                          __float_as_uint(vals[i]));
        }
    }
}

// gather body: rows padded to multiple of 4 (zeroed slots) -> remainder-free
// unroll-4 loop, 8 row loads + 2 edge-record loads in flight. VGPR fits 64.
__device__ __forceinline__ void gather16(const ushort_t* __restrict__ srcbf,
                                         const uint2* __restrict__ e_cv,
                                         int beg, int end, float* acc) {
    for (int e = beg; e < end; e += 4) {
        uint4 E0 = *(const uint4*)(e_cv + e);        // {c0,w0,c1,w1}
        uint4 E1 = *(const uint4*)(e_cv + e + 2);    // {c2,w2,c3,w3}
        float w0 = __uint_as_float(E0.y), w1 = __uint_as_float(E0.w);
        float w2 = __uint_as_float(E1.y), w3 = __uint_as_float(E1.w);
        const ushort_t* p0 = srcbf + ((size_t)E0.x * 512);
        const ushort_t* p1 = srcbf + ((size_t)E0.z * 512);
        const ushort_t* p2 = srcbf + ((size_t)E1.x * 512);
        const ushort_t* p3 = srcbf + ((size_t)E1.z * 512);
        uint4 a0 = *(const uint4*)p0, b0 = *(const uint4*)(p0 + 8);
        uint4 a1 = *(const uint4*)p1, b1 = *(const uint4*)(p1 + 8);
        uint4 a2 = *(const uint4*)p2, b2 = *(const uint4*)(p2 + 8);
        uint4 a3 = *(const uint4*)p3, b3 = *(const uint4*)(p3 + 8);
        fma8(acc, w0, a0); fma8(acc + 8, w0, b0);
        fma8(acc, w1, a1); fma8(acc + 8, w1, b1);
        fma8(acc, w2, a2); fma8(acc + 8, w2, b2);
        fma8(acc, w3, a3); fma8(acc + 8, w3, b3);
    }
}

__device__ __forceinline__ int row_end(const int* cursor, int v) {
    int c = cursor[v];
    if (c > CAP_) c = CAP_;
    return v * CAP_ + ((c + 3) & ~3);
}

// ---------------- phase-2 unit: x1 = L @ x0t (8 vertices per unit) ----------------
__device__ __forceinline__ void spmm1_unit(int u, int t,
                                           const ushort_t* __restrict__ x0t,
                                           const int* __restrict__ cursor,
                                           const uint2* __restrict__ e_cv,
                                           ushort_t* __restrict__ x1) {
    int vi = t >> 5, b = (t >> 2) & 7, f8 = t & 3;
    int v = u * 8 + vi;
    float acc[16];
    #pragma unroll
    for (int i = 0; i < 16; i++) acc[i] = 0.f;
    gather16(x0t + b * 64 + f8 * 16, e_cv, v * CAP_, row_end(cursor, v), acc);
    unsigned int opk[8];
    #pragma unroll
    for (int i = 0; i < 8; i++) opk[i] = pack2(acc[2 * i], acc[2 * i + 1]);
    ushort_t* dst = x1 + ((size_t)v * 8 + b) * 64 + f8 * 16;
    *(uint4*)dst       = make_uint4(opk[0], opk[1], opk[2], opk[3]);
    *(uint4*)(dst + 8) = make_uint4(opk[4], opk[5], opk[6], opk[7]);
}

// ---------------- phase-3 unit: g = L@x1 (LDS) + 64-row GEMM + bias + out ----------
// out = x0*(W0-W2) + x1*W1 + g*(2*W2)   (weight fold done in prep_w)
__device__ __forceinline__ void spmm2_unit(int u, int t,
                                           const ushort_t* __restrict__ x0t,
                                           const ushort_t* __restrict__ x1,
                                           const int* __restrict__ cursor,
                                           const uint2* __restrict__ e_cv,
                                           const ushort_t* __restrict__ wBf,
                                           const float* __restrict__ bias,
                                           float* __restrict__ out) {
    __shared__ ushort_t sh[64 * 72];        // g rows, padded stride 72 shorts (144 B)
    int lane = t & 63, wv = t >> 6;
    int quad = lane >> 4, col = lane & 15;
    int v0 = u * 8;
    int m0 = v0 * 8 + wv * 16;

    // Prefetch GEMM A-fragments (own rows of x0, x1) — overlaps the gather phase.
    size_t arow = (size_t)(m0 + col) * 64 + quad * 8;   // A: row=lane&15, k=quad*8+j
    short8 A0[2], A1[2];
    A0[0] = *(const short8*)(x0t + arow);
    A0[1] = *(const short8*)(x0t + arow + 32);
    A1[0] = *(const short8*)(x1 + arow);
    A1[1] = *(const short8*)(x1 + arow + 32);

    int vi = t >> 5, b = (t >> 2) & 7, f8 = t & 3;
    int v = v0 + vi;
    float acc[16];
    #pragma unroll
    for (int i = 0; i < 16; i++) acc[i] = 0.f;
    gather16(x1 + b * 64 + f8 * 16, e_cv, v * CAP_, row_end(cursor, v), acc);

    // g straight to LDS (no x0 blend — folded into weights)
    unsigned int opk[8];
    #pragma unroll
    for (int i = 0; i < 8; i++) opk[i] = pack2(acc[2 * i], acc[2 * i + 1]);
    int mg = vi * 8 + b;
    ushort_t* dst = sh + mg * 72 + f8 * 16;
    *(uint4*)dst       = make_uint4(opk[0], opk[1], opk[2], opk[3]);
    *(uint4*)(dst + 8) = make_uint4(opk[4], opk[5], opk[6], opk[7]);
    __syncthreads();

    // ---- GEMM phase: wave wv handles rows [wv*16, wv*16+16) of this 64-row tile
    short8 Bf[6][4];
    #pragma unroll
    for (int kb = 0; kb < 6; kb++)
        #pragma unroll
        for (int ntc = 0; ntc < 4; ntc++)
            Bf[kb][ntc] = *(const short8*)(wBf + ((size_t)((kb * 4 + ntc) * 64 + lane)) * 8);

    float bv[4];
    #pragma unroll
    for (int ntc = 0; ntc < 4; ntc++) bv[ntc] = bias[ntc * 16 + col];

    float4v accm[4];
    #pragma unroll
    for (int ntc = 0; ntc < 4; ntc++) accm[ntc] = (float4v){0.f, 0.f, 0.f, 0.f};

    #pragma unroll
    for (int p = 0; p < 2; p++) {
        #pragma unroll
        for (int ntc = 0; ntc < 4; ntc++)
            accm[ntc] = __builtin_amdgcn_mfma_f32_16x16x32_bf16(A0[p], Bf[p][ntc], accm[ntc], 0, 0, 0);
    }
    #pragma unroll
    for (int p = 0; p < 2; p++) {
        #pragma unroll
        for (int ntc = 0; ntc < 4; ntc++)
            accm[ntc] = __builtin_amdgcn_mfma_f32_16x16x32_bf16(A1[p], Bf[2 + p][ntc], accm[ntc], 0, 0, 0);
    }
    #pragma unroll
    for (int p = 0; p < 2; p++) {
        short8 A = *(const short8*)(sh + (wv * 16 + col) * 72 + quad * 8 + p * 32);
        #pragma unroll
        for (int ntc = 0; ntc < 4; ntc++)
            accm[ntc] = __builtin_amdgcn_mfma_f32_16x16x32_bf16(A, Bf[4 + p][ntc], accm[ntc], 0, 0, 0);
    }

    #pragma unroll
    for (int reg = 0; reg < 4; reg++) {
        int m = m0 + quad * 4 + reg;        // C/D: row = quad*4+reg, col = lane&15
        int vv = m >> 3, bb = m & 7;
        float* orow = out + ((size_t)bb * V_ + vv) * 64;
        #pragma unroll
        for (int ntc = 0; ntc < 4; ntc++)
            orow[ntc * 16 + col] = accm[ntc][reg] + bv[ntc];
    }
    __syncthreads();   // protect sh before next grid-stride iteration rewrites it
}

// ---------------- standalone fallback kernels ----------------
__global__ __launch_bounds__(256) void k1_fused(const float* __restrict__ inp,
                                                ushort_t* __restrict__ x0t,
                                                const int* __restrict__ rows,
                                                const int* __restrict__ cols,
                                                const float* __restrict__ vals, int nnz,
                                                int* __restrict__ cursor,
                                                uint2* __restrict__ e_cv,
                                                const float* __restrict__ wgt,
                                                ushort_t* __restrict__ wBf) {
    k1_unit(blockIdx.x, threadIdx.x, inp, x0t, rows, cols, vals, nnz, cursor, e_cv, wgt, wBf);
}

__global__ __launch_bounds__(256) void spmm1_kernel(const ushort_t* __restrict__ x0t,
                                                    const int* __restrict__ cursor,
                                                    const uint2* __restrict__ e_cv,
                                                    ushort_t* __restrict__ x1) {
    spmm1_unit(blockIdx.x, threadIdx.x, x0t, cursor, e_cv, x1);
}

__global__ __launch_bounds__(256) void spmm2_gemm(const ushort_t* __restrict__ x0t,
                                                  const ushort_t* __restrict__ x1,
                                                  const int* __restrict__ cursor,
                                                  const uint2* __restrict__ e_cv,
                                                  const ushort_t* __restrict__ wBf,
                                                  const float* __restrict__ bias,
                                                  float* __restrict__ out) {
    spmm2_unit(blockIdx.x, threadIdx.x, x0t, x1, cursor, e_cv, wBf, bias, out);
}

// ---------------- cooperative mega-kernel: whole pipeline, one dispatch ----------
// NO min-occupancy clause: round 5 showed __launch_bounds__(256,8) caps VGPR -> scratch
// spill (VGPR=32, ~2GB scratch traffic, 1385us). Let the allocator take ~64-72 VGPR and
// size the grid from the occupancy query instead.
struct KArgs {
    const float* inp; const float* wgt; const float* bias;
    const int* rows; const int* cols; const float* vals;
    int nnz; int hb;
    int* cursor; uint2* e_cv;
    ushort_t* x0t; ushort_t* x1; ushort_t* wBf;
    float* out;
    uint4* zbase; long long z16;
};

__global__ __launch_bounds__(256) void mega_kernel(KArgs a) {
    cg::grid_group grid = cg::this_grid();
    int t = threadIdx.x;
    int G = gridDim.x;
    // phase 0: zero cursor + e_cv (pads must read {0,0})
    for (long long i = (long long)blockIdx.x * 256 + t; i < a.z16; i += (long long)G * 256)
        a.zbase[i] = make_uint4(0u, 0u, 0u, 0u);
    grid.sync();
    // phase 1: conv | prep_w | bucket
    int n1 = PREP_B + 48 + a.hb;
    for (int u = blockIdx.x; u < n1; u += G)
        k1_unit(u, t, a.inp, a.x0t, a.rows, a.cols, a.vals, a.nnz, a.cursor, a.e_cv, a.wgt, a.wBf);
    grid.sync();
    // phase 2: x1 = L @ x0
    for (int u = blockIdx.x; u < V_ / 8; u += G)
        spmm1_unit(u, t, a.x0t, a.cursor, a.e_cv, a.x1);
    grid.sync();
    // phase 3: g = L @ x1, GEMM, out
    for (int u = blockIdx.x; u < V_ / 8; u += G)
        spmm2_unit(u, t, a.x0t, a.x1, a.cursor, a.e_cv, a.wBf, a.bias, a.out);
}

extern "C" void kernel_launch(void* const* d_in, const int* in_sizes, int n_in,
                              void* d_out, int out_size, void* d_ws, size_t ws_size,
                              hipStream_t stream) {
    const float* inp  = (const float*)d_in[0];
    const float* wgt  = (const float*)d_in[1];
    const float* bias = (const float*)d_in[2];
    const int*   rows = (const int*)d_in[3];
    const int*   cols = (const int*)d_in[4];
    const float* vals = (const float*)d_in[5];
    int nnz = in_sizes[3];
    float* out = (float*)d_out;
    (void)n_in; (void)out_size;

    char* ws = (char*)d_ws;
    size_t o = 0;
    auto alloc = [&](size_t bytes) { void* p = ws + o; o += (bytes + 255) & ~(size_t)255; return p; };
    size_t meta0 = o;
    int*      cursor = (int*)alloc((size_t)V_ * 4);
    uint2*    e_cv   = (uint2*)alloc((size_t)V_ * CAP_ * 8);
    size_t meta_bytes = o - meta0;
    ushort_t* x0t    = (ushort_t*)alloc((size_t)M_ * 64 * 2);
    ushort_t* x1     = (ushort_t*)alloc((size_t)M_ * 64 * 2);
    ushort_t* wBf    = (ushort_t*)alloc(6 * 4 * 64 * 8 * 2);

    if (ws_size < o) {
        fill_sentinel<<<(M_ * 64 + 255) / 256, 256, 0, stream>>>(out, M_ * 64);
        return;
    }

    int hb = (nnz + 255) / 256;

    // Cooperative co-residency: occupancy query (cached), 256 CUs on MI355X.
    static int maxBlkPerCU = -2;
    if (maxBlkPerCU == -2) {
        int mb = 0;
        hipError_t e = hipOccupancyMaxActiveBlocksPerMultiprocessor(&mb, mega_kernel, 256, 0);
        maxBlkPerCU = (e == hipSuccess && mb > 0) ? mb : 0;
    }
    bool done = false;
    if (maxBlkPerCU > 0) {
        int G = maxBlkPerCU * 256;
        if (G > 2048) G = 2048;
        KArgs a;
        a.inp = inp; a.wgt = wgt; a.bias = bias;
        a.rows = rows; a.cols = cols; a.vals = vals;
        a.nnz = nnz; a.hb = hb;
        a.cursor = cursor; a.e_cv = e_cv;
        a.x0t = x0t; a.x1 = x1; a.wBf = wBf;
        a.out = out;
        a.zbase = (uint4*)(ws + meta0);
        a.z16 = (long long)(meta_bytes / 16);
        void* kargs[] = { &a };
        hipError_t e = hipLaunchCooperativeKernel((const void*)mega_kernel,
                                                  dim3(G), dim3(256), kargs, 0, stream);
        done = (e == hipSuccess);
    }
    if (!done) {
        // fallback: 4-node stream pipeline (round-3/4 style, pad-4 gather)
        hipMemsetAsync((char*)ws + meta0, 0, meta_bytes, stream);
        k1_fused<<<PREP_B + 48 + hb, 256, 0, stream>>>(inp, x0t, rows, cols, vals, nnz,
                                                       cursor, e_cv, wgt, wBf);
        spmm1_kernel<<<V_ / 8, 256, 0, stream>>>(x0t, cursor, e_cv, x1);
        spmm2_gemm<<<V_ / 8, 256, 0, stream>>>(x0t, x1, cursor, e_cv, wBf, bias, out);
    }
}